// Round 6
// baseline (43.475 us; speedup 1.0000x reference)
//
#include <hip/hip_runtime.h>
#include <hip/hip_bf16.h>

// MicrotubuleAttention — exact algebraic reduction + bf16 MFMA.
//
// GTP penalty: (1 - exp(-gamma*dist))*(-1e9), gamma >= 1e-4 => every
// off-diagonal softmax argument <= -9.9e4 => expf underflows to exactly 0.
// Softmax is exactly one-hot at k==q, so attention output == V_rep and
//   out = (x @ Wv) @ Weff        (4.3 GFLOP total)
// with Weff[c][m] = sum_{r=0..3} Wo[(4*(c>>6)+r)*64 + (c&63)][m]  (GQA fold).
// RoPE/Q/K/polarity are dead code.  Pipeline (3 launches):
//   1. prepW: WvT = bf16(Wv^T); WeffT = bf16(fold(Wo)^T)      (weights only)
//   2. Vb    = cvt(x) @ WvT^T   (MFMA; A reg-staged f32->bf16) [4096,256]
//   3. out   = Vb @ WeffT^T     (MFMA, f32 out)                [4096,1024]
// x is consumed as f32 directly by the GEMM (no xb round trip).

using bf16x8 = __attribute__((ext_vector_type(8))) short;
using f32x4  = __attribute__((ext_vector_type(4))) float;

static constexpr int DMODEL = 1024;
static constexpr int KVDIM  = 256;   // H_KV * D_HEAD
static constexpr int ROWS   = 4096;  // B * T

__device__ inline unsigned short f2bf(float f) {
    __hip_bfloat16 h = __float2bfloat16(f);   // RNE
    return *reinterpret_cast<unsigned short*>(&h);
}

// ---- weights prep: block-range partitioned ------------------------------
static constexpr int WVT_BLOCKS  = (DMODEL * KVDIM) / 256;   // 1024
static constexpr int FOLD_BLOCKS = (DMODEL * KVDIM) / 256;   // 1024

__global__ void prepw_kernel(const float* __restrict__ Wv,
                             const float* __restrict__ Wo,
                             unsigned short* __restrict__ WvT,
                             unsigned short* __restrict__ WeffT) {
    const int b = blockIdx.x;
    const int t = threadIdx.x;
    if (b < WVT_BLOCKS) {
        // WvT[c][d] = bf16(Wv[d][c])
        int idx = b * 256 + t;                     // 256K
        int d = idx & (DMODEL - 1);
        int c = idx >> 10;
        WvT[idx] = f2bf(Wv[(size_t)d * KVDIM + c]);
    } else {
        // WeffT[m][c] = bf16( sum_{r} Wo[(4*(c>>6)+r)*64 + (c&63)][m] )
        int idx = (b - WVT_BLOCKS) * 256 + t;      // 256K
        int c = idx & (KVDIM - 1);
        int m = idx >> 8;
        const float* base =
            Wo + (size_t)((c >> 6) * 4 * 64 + (c & 63)) * DMODEL + m;
        float s = base[0]
                + base[(size_t) 64 * DMODEL]
                + base[(size_t)128 * DMODEL]
                + base[(size_t)192 * DMODEL];
        WeffT[(size_t)m * KVDIM + c] = f2bf(s);
    }
}

// ---- gemmA: Vb[4096][256] = bf16(x) @ WvT^T ------------------------------
// BM=BN=64, BK=64; 4 waves 2x2, wave tile 32x32 (AM=AN=2).
// A is reg-staged from f32 x: global_load_dwordx4 -> cvt -> ds_write_b128
// (issue-early / write-late so HBM latency hides under MFMA).
// B staged via global_load_lds. 2-buffer LDS, barrier at top of step.
__launch_bounds__(256, 1)
__global__ void gemm_xwv(const float* __restrict__ X,
                         const unsigned short* __restrict__ WvT,
                         unsigned short* __restrict__ Vb) {
    __shared__ short As[2][64 * 64];   // [row][k], 8 KB each
    __shared__ short Bs[2][64 * 64];   // [col][k], 8 KB each

    // T1: XCD-chunked swizzle (nwg = 256, %8==0)
    const int gx  = gridDim.x;                    // 4
    const int nwg = gx * gridDim.y;               // 256
    const int bid = blockIdx.y * gx + blockIdx.x;
    const int cpx = nwg >> 3;
    const int swz = (bid & 7) * cpx + (bid >> 3);
    const int brow = (swz / gx) * 64;
    const int bcol = (swz % gx) * 64;

    const int tid  = threadIdx.x;
    const int lane = tid & 63;
    const int w    = tid >> 6;
    const int wr   = w >> 1;
    const int wc   = w & 1;

    const int trow = tid >> 2;          // A staging: row 0..63
    const int tk16 = (tid & 3) * 16;    // 16 consecutive k per thread
    const int col8 = lane >> 3;         // B staging
    const int koff = (lane & 7) * 8;
    const int lr   = lane & 15;
    const int kg   = (lane >> 4) * 8;

    f32x4 acc[2][2] = {};
    float4 av0, av1, av2, av3;

    auto loadA = [&](int kt) {
        const float* p = X + (size_t)(brow + trow) * DMODEL + kt + tk16;
        av0 = *reinterpret_cast<const float4*>(p);
        av1 = *reinterpret_cast<const float4*>(p + 4);
        av2 = *reinterpret_cast<const float4*>(p + 8);
        av3 = *reinterpret_cast<const float4*>(p + 12);
    };
    auto writeA = [&](int buf) {
        bf16x8 lo, hi;
        lo[0] = (short)f2bf(av0.x); lo[1] = (short)f2bf(av0.y);
        lo[2] = (short)f2bf(av0.z); lo[3] = (short)f2bf(av0.w);
        lo[4] = (short)f2bf(av1.x); lo[5] = (short)f2bf(av1.y);
        lo[6] = (short)f2bf(av1.z); lo[7] = (short)f2bf(av1.w);
        hi[0] = (short)f2bf(av2.x); hi[1] = (short)f2bf(av2.y);
        hi[2] = (short)f2bf(av2.z); hi[3] = (short)f2bf(av2.w);
        hi[4] = (short)f2bf(av3.x); hi[5] = (short)f2bf(av3.y);
        hi[6] = (short)f2bf(av3.z); hi[7] = (short)f2bf(av3.w);
        *reinterpret_cast<bf16x8*>(&As[buf][trow * 64 + tk16])     = lo;
        *reinterpret_cast<bf16x8*>(&As[buf][trow * 64 + tk16 + 8]) = hi;
    };
    auto stageB = [&](int buf, int kt) {
        #pragma unroll
        for (int i = 0; i < 2; ++i) {
            const int ch = w * 2 + i;                       // 0..7
            const unsigned short* g =
                WvT + (size_t)(bcol + ch * 8 + col8) * DMODEL + kt + koff;
            __builtin_amdgcn_global_load_lds(
                (const __attribute__((address_space(1))) void*)g,
                (__attribute__((address_space(3))) void*)(&Bs[buf][ch * 512]),
                16, 0, 0);
        }
    };

    // prologue: tile 0
    loadA(0);
    stageB(0, 0);
    writeA(0);                    // compiler waits av deps (B stays in flight)

    constexpr int nt = DMODEL / 64;   // 16
    int cur = 0;
    for (int t = 0; t < nt; ++t) {
        __syncthreads();          // vmcnt(0)+lgkmcnt(0)+barrier: publishes cur
        if (t + 1 < nt) {
            loadA((t + 1) * 64);          // issue early (regs)
            stageB(cur ^ 1, (t + 1) * 64);
        }
        #pragma unroll
        for (int ks = 0; ks < 2; ++ks) {
            bf16x8 a[2], b[2];
            #pragma unroll
            for (int m = 0; m < 2; ++m)
                a[m] = *reinterpret_cast<const bf16x8*>(
                    &As[cur][(wr * 32 + m * 16 + lr) * 64 + ks * 32 + kg]);
            #pragma unroll
            for (int n = 0; n < 2; ++n)
                b[n] = *reinterpret_cast<const bf16x8*>(
                    &Bs[cur][(wc * 32 + n * 16 + lr) * 64 + ks * 32 + kg]);
            #pragma unroll
            for (int m = 0; m < 2; ++m)
                #pragma unroll
                for (int n = 0; n < 2; ++n)
                    acc[m][n] = __builtin_amdgcn_mfma_f32_16x16x32_bf16(
                        a[m], b[n], acc[m][n], 0, 0, 0);
        }
        if (t + 1 < nt) writeA(cur ^ 1);  // write late; waits own av only
        cur ^= 1;
    }

    // C/D layout: col = lane&15, row = (lane>>4)*4 + reg
    const int rg = (lane >> 4) * 4;
    #pragma unroll
    for (int m = 0; m < 2; ++m)
        #pragma unroll
        for (int n = 0; n < 2; ++n)
            #pragma unroll
            for (int j = 0; j < 4; ++j) {
                const size_t row = brow + wr * 32 + m * 16 + rg + j;
                const size_t col = bcol + wc * 32 + n * 16 + lr;
                Vb[row * KVDIM + col] = f2bf(acc[m][n][j]);
            }
}

// ---- gemmB: C[M][N] = A[M][K] @ Bt[N][K]^T  (R5-verified structure) ------
// BM=128, BN=64, BK=64; triple-buffered LDS, depth-2 prefetch, counted
// vmcnt, ONE s_barrier per K-step.
template<int AM, int AN, bool OUT_BF16>
__launch_bounds__(256, 2)
__global__ void gemm_bf16_mfma(const unsigned short* __restrict__ A,
                               const unsigned short* __restrict__ Bt,
                               void* __restrict__ Cout,
                               int M, int N, int K) {
    constexpr int BM  = 2 * AM * 16;
    constexpr int BN  = 2 * AN * 16;
    constexpr int ACH = BM / 32;
    constexpr int BCH = BN / 32;
    constexpr int LP  = ACH + BCH;

    __shared__ short As[3][BM * 64];
    __shared__ short Bs[3][BN * 64];

    const int gx  = gridDim.x;
    const int nwg = gx * gridDim.y;
    const int bid = blockIdx.y * gx + blockIdx.x;
    const int cpx = nwg >> 3;
    const int swz = (bid & 7) * cpx + (bid >> 3);
    const int brow = (swz / gx) * BM;
    const int bcol = (swz % gx) * BN;

    const int tid  = threadIdx.x;
    const int lane = tid & 63;
    const int w    = tid >> 6;
    const int wr   = w >> 1;
    const int wc   = w & 1;

    const int lrow8 = lane >> 3;
    const int lkoff = (lane & 7) * 8;
    const int lr    = lane & 15;
    const int kg    = (lane >> 4) * 8;

    f32x4 acc[AM][AN] = {};

    auto stage = [&](int buf, int kt) {
        #pragma unroll
        for (int i = 0; i < ACH; ++i) {
            const int ch = w * ACH + i;
            const unsigned short* g =
                A + (size_t)(brow + ch * 8 + lrow8) * K + kt + lkoff;
            __builtin_amdgcn_global_load_lds(
                (const __attribute__((address_space(1))) void*)g,
                (__attribute__((address_space(3))) void*)(&As[buf][ch * 512]),
                16, 0, 0);
        }
        #pragma unroll
        for (int i = 0; i < BCH; ++i) {
            const int ch = w * BCH + i;
            const unsigned short* g =
                Bt + (size_t)(bcol + ch * 8 + lrow8) * K + kt + lkoff;
            __builtin_amdgcn_global_load_lds(
                (const __attribute__((address_space(1))) void*)g,
                (__attribute__((address_space(3))) void*)(&Bs[buf][ch * 512]),
                16, 0, 0);
        }
    };

    const int nt = K >> 6;
    stage(0, 0);
    stage(1, 64);
    int bc = 0;
    for (int t = 0; t < nt; ++t) {
        if (t + 1 < nt) {
            if constexpr (LP == 6)
                asm volatile("s_waitcnt vmcnt(6)" ::: "memory");
            else
                asm volatile("s_waitcnt vmcnt(4)" ::: "memory");
        } else {
            asm volatile("s_waitcnt vmcnt(0)" ::: "memory");
        }
        __builtin_amdgcn_s_barrier();

        int bs = bc + 2; if (bs >= 3) bs -= 3;
        if (t + 2 < nt) stage(bs, (t + 2) << 6);

        #pragma unroll
        for (int ks = 0; ks < 2; ++ks) {
            bf16x8 a[AM], b[AN];
            #pragma unroll
            for (int m = 0; m < AM; ++m)
                a[m] = *reinterpret_cast<const bf16x8*>(
                    &As[bc][(wr * AM * 16 + m * 16 + lr) * 64 + ks * 32 + kg]);
            #pragma unroll
            for (int n = 0; n < AN; ++n)
                b[n] = *reinterpret_cast<const bf16x8*>(
                    &Bs[bc][(wc * AN * 16 + n * 16 + lr) * 64 + ks * 32 + kg]);
            #pragma unroll
            for (int m = 0; m < AM; ++m)
                #pragma unroll
                for (int n = 0; n < AN; ++n)
                    acc[m][n] = __builtin_amdgcn_mfma_f32_16x16x32_bf16(
                        a[m], b[n], acc[m][n], 0, 0, 0);
        }
        bc = (bc == 2) ? 0 : bc + 1;
    }

    const int rg = (lane >> 4) * 4;
    #pragma unroll
    for (int m = 0; m < AM; ++m) {
        #pragma unroll
        for (int n = 0; n < AN; ++n) {
            #pragma unroll
            for (int j = 0; j < 4; ++j) {
                const size_t row = brow + wr * AM * 16 + m * 16 + rg + j;
                const size_t col = bcol + wc * AN * 16 + n * 16 + lr;
                if (OUT_BF16)
                    ((unsigned short*)Cout)[row * N + col] = f2bf(acc[m][n][j]);
                else
                    ((float*)Cout)[row * N + col] = acc[m][n][j];
            }
        }
    }
}

extern "C" void kernel_launch(void* const* d_in, const int* in_sizes, int n_in,
                              void* d_out, int out_size, void* d_ws, size_t ws_size,
                              hipStream_t stream) {
    const float* x  = (const float*)d_in[0];   // (4096, 1024)
    const float* Wv = (const float*)d_in[3];   // (1024, 256)
    const float* Wo = (const float*)d_in[4];   // (1024, 1024)
    float* out = (float*)d_out;                // (4096, 1024) f32

    unsigned short* WvT   = (unsigned short*)d_ws;           // 0.5 MB [c][d]
    unsigned short* WeffT = WvT   + (size_t)KVDIM * DMODEL;  // 0.5 MB [m][c]
    unsigned short* Vb    = WeffT + (size_t)DMODEL * KVDIM;  // 2 MB   [r][c]

    prepw_kernel<<<WVT_BLOCKS + FOLD_BLOCKS, 256, 0, stream>>>(
        Wv, Wo, WvT, WeffT);

    // Vb[r][c] = sum_d bf16(x[r][d]) * WvT[c][d]   (M=4096, N=256, K=1024)
    gemm_xwv<<<dim3(KVDIM / 64, ROWS / 64), 256, 0, stream>>>(x, WvT, Vb);

    // out[r][m] = sum_c Vb[r][c] * WeffT[m][c]     (M=4096, N=1024, K=256)
    gemm_bf16_mfma<4, 2, false><<<dim3(DMODEL / 64, ROWS / 128), 256, 0, stream>>>(
        Vb, WeffT, out, ROWS, DMODEL, KVDIM);
}